// Round 5
// baseline (136.922 us; speedup 1.0000x reference)
//
#include <hip/hip_runtime.h>
#include <hip/hip_bf16.h>

#define NB   16     // B
#define NN   512    // MAX_N
#define NE   1024   // MAX_E
#define NBETA 64    // MAX_BETA
#define NHID 128
#define GRID 512    // 2 blocks/CU x 256 CU — exact co-residency for the barrier

typedef __attribute__((ext_vector_type(8))) short short8;
typedef __attribute__((ext_vector_type(4))) float f32x4;

static __device__ __forceinline__ unsigned short f2bf(float f) {
    unsigned u = __float_as_uint(f);
    return (unsigned short)((u + 0x7fffu + ((u >> 16) & 1u)) >> 16);   // RNE
}

static __device__ __forceinline__ f32x4 splat4(float v) {
    f32x4 r; r.x = v; r.y = v; r.z = v; r.w = v; return r;
}

// ---------------------------------------------------------------------------
// ONE regular (graph-capturable) kernel, 512 blocks x 512 thr, 64 KB LDS.
// Co-residency: 512 blocks = exactly 2/CU (LDS 128/160 KB, VGPR<=128 via
// __launch_bounds__(512,4), 16 waves/CU) -> manual grid barrier is safe.
// ctr is zeroed by a hipMemsetAsync node before the kernel each iteration.
//
// Phase 1: 2 (b,beta) tasks/block (256 thr each, wave-shfl butterfly) ->
//   base[] = emb@W3[:64]+b3 ; 96 weight elems/block -> bf16 swizzled wsT[].
// [grid barrier: threadfence-all / syncthreads / tid0 arrive+spin / sync]
// Phase 2: per 32-edge tile (b = bid&15 interleave). Padded tiles zero-store
//   and retire. Phase E (VALU) + 3 bf16 MFMA layers, W4/W5/W6 register-
//   prefetched and committed to LDS post-barrier. Identical math to the
//   verified R4 k_fused.
// Workspace: base 512 KB | wsT 96 KB | ctr 4 B.
// ---------------------------------------------------------------------------
__global__ __launch_bounds__(512, 4) void k_all(
        const float* __restrict__ x, const int* __restrict__ ei,
        const float* __restrict__ SCB,
        const int* __restrict__ elen, const int* __restrict__ blen,
        const float* __restrict__ W1, const float* __restrict__ b1,
        const float* __restrict__ W2, const float* __restrict__ b2,
        const float* __restrict__ W3, const float* __restrict__ b3,
        const float* __restrict__ W4, const float* __restrict__ b4,
        const float* __restrict__ W5, const float* __restrict__ b5,
        const float* __restrict__ W6, const float* __restrict__ b6,
        float* __restrict__ base, unsigned short* __restrict__ wsT,
        unsigned int* __restrict__ ctr, float* __restrict__ out) {
    __shared__ __align__(16) char lds[65536];
    int bid = blockIdx.x, tid = threadIdx.x;

    // ---------------- Phase 1a: weight transform (96 elems/block) ----------
    if (tid < 96) {
        int j = bid * 96 + tid;                       // 0..49151
        int w = j >> 14, rem = j & 16383;
        int k = rem & 127, n = rem >> 7;
        const float* W = (w == 0) ? W4 : ((w == 1) ? W5 : W6);
        float v = W[k * NHID + n];
        int byte = n * 256 + ((2 * k) ^ ((n & 7) << 4));
        *reinterpret_cast<unsigned short*>(
            reinterpret_cast<char*>(wsT) + (size_t)w * 32768 + byte) = f2bf(v);
    }

    // ---------------- Phase 1b: two (b,beta) tasks per block ---------------
    {
        int hf = tid >> 8, t = tid & 255;             // task, lane-in-task
        int bb = bid * 2 + hf;                        // 0..1023
        int b = bb >> 6, beta = bb & 63;
        int el = elen[b], bl = blen[b];
        float a0 = 0, a1 = 0, a2 = 0, a3 = 0;
        if (beta < bl) {
            const float* row = SCB + (size_t)bb * NE;
            const int* eis = ei + b * 2 * NE;
            const float* xb = x + b * NN * 2;
            for (int e = t; e < el; e += 256) {
                float tt = fabsf(row[e]);
                int s0 = eis[e], s1 = eis[NE + e];
                float2 v0 = *reinterpret_cast<const float2*>(xb + 2 * s0);
                float2 v1 = *reinterpret_cast<const float2*>(xb + 2 * s1);
                a0 = fmaf(tt, v0.x, a0);
                a1 = fmaf(tt, v0.y, a1);
                a2 = fmaf(tt, v1.x, a2);
                a3 = fmaf(tt, v1.y, a3);
            }
        }
        #pragma unroll
        for (int off = 32; off > 0; off >>= 1) {      // wave64 butterfly
            a0 += __shfl_down(a0, off);
            a1 += __shfl_down(a1, off);
            a2 += __shfl_down(a2, off);
            a3 += __shfl_down(a3, off);
        }
        float* part = reinterpret_cast<float*>(lds);          // [8 waves][4]
        if ((tid & 63) == 0) {
            int w8 = tid >> 6;
            part[w8 * 4 + 0] = a0; part[w8 * 4 + 1] = a1;
            part[w8 * 4 + 2] = a2; part[w8 * 4 + 3] = a3;
        }
        __syncthreads();
        float* h1s  = reinterpret_cast<float*>(lds + 128);    // [2][64]
        float* embs = reinterpret_cast<float*>(lds + 640);    // [2][64]
        if (t < 64) {
            float v = b1[t];
            #pragma unroll
            for (int i = 0; i < 4; ++i) {
                float si = part[(hf * 4 + 0) * 4 + i] + part[(hf * 4 + 1) * 4 + i]
                         + part[(hf * 4 + 2) * 4 + i] + part[(hf * 4 + 3) * 4 + i];
                v = fmaf(si, W1[i * 64 + t], v);
            }
            h1s[hf * 64 + t] = fmaxf(v, 0.f);
        }
        __syncthreads();
        if (t < 64) {
            float v = b2[t];
            #pragma unroll 8
            for (int k = 0; k < 64; ++k)
                v = fmaf(h1s[hf * 64 + k], W2[k * 64 + t], v);
            embs[hf * 64 + t] = v;
        }
        __syncthreads();
        if (t < 128) {
            float v = b3[t];
            #pragma unroll 8
            for (int k = 0; k < 64; ++k)
                v = fmaf(embs[hf * 64 + k], W3[k * NHID + t], v);
            base[(size_t)bb * NHID + t] = v;
        }
    }

    // ---------------- manual grid barrier (all 512 blocks co-resident) -----
    __threadfence();                     // release this thread's global writes
    __syncthreads();                     // all threads of block fenced
    if (tid == 0) {
        atomicAdd(ctr, 1u);              // device-scope arrive
        while (__hip_atomic_load(ctr, __ATOMIC_ACQUIRE,
                                 __HIP_MEMORY_SCOPE_AGENT) < (unsigned)GRID)
            __builtin_amdgcn_s_sleep(2);
    }
    __syncthreads();

    // ---------------- Phase 2: fused 32-edge tile per block ----------------
    int b = bid & 15;
    int e0 = (bid >> 4) * 32;
    int el = elen[b];
    if (e0 >= el) {                       // fully-padded tile: zero and retire
        float4 z; z.x = 0.f; z.y = 0.f; z.z = 0.f; z.w = 0.f;
        float4* o4 = reinterpret_cast<float4*>(out) + (size_t)(b * NE + e0) * 32;
        o4[tid] = z;
        o4[tid + 512] = z;
        return;
    }
    int bl = blen[b];

    float* baseS = reinterpret_cast<float*>(lds);             // 32K, dead after E
    char*  wS    = lds + 32768;                               // 32K
    float4* efS  = reinterpret_cast<float4*>(wS);             // 512 B
    float* w3r   = reinterpret_cast<float*>(wS + 512);        // 2 K
    float* tS    = reinterpret_cast<float*>(wS + 8192);       // 8 K [beta][32]
    char* io0 = lds;                                          // 8K A / L5 out
    char* io1 = lds + 8192;                                   // 8K L4 out

    const float4* w4src = reinterpret_cast<const float4*>(wsT);
    const float4* w5src = reinterpret_cast<const float4*>(
        reinterpret_cast<const char*>(wsT) + 32768);
    const float4* w6src = reinterpret_cast<const float4*>(
        reinterpret_cast<const char*>(wsT) + 65536);
    float4 pw0, pw1, pw2, pw3;            // in-flight weight tile

    {   // stage (base, |SCB| tile, edge feats, W3 rows 64..67) + W4 prefetch
        const float4* bsrc = reinterpret_cast<const float4*>(
            base + (size_t)b * NBETA * NHID);
        float4* bd = reinterpret_cast<float4*>(baseS);
        #pragma unroll
        for (int i = 0; i < 4; ++i) bd[tid + 512 * i] = bsrc[tid + 512 * i];
        {
            int row = tid >> 3, c4 = tid & 7;
            float4 v = *reinterpret_cast<const float4*>(
                SCB + (size_t)(b * NBETA + row) * NE + e0 + c4 * 4);
            v.x = fabsf(v.x); v.y = fabsf(v.y); v.z = fabsf(v.z); v.w = fabsf(v.w);
            reinterpret_cast<float4*>(tS)[tid] = v;
        }
        if (tid < 64) {
            int e = tid >> 1, hf2 = tid & 1;
            int idx = ei[b * 2 * NE + hf2 * NE + e0 + e];
            float2 v2 = *reinterpret_cast<const float2*>(x + b * NN * 2 + idx * 2);
            reinterpret_cast<float2*>(&efS[e])[hf2] = v2;
        }
        w3r[tid] = W3[64 * NHID + tid];
        pw0 = w4src[tid];        pw1 = w4src[tid + 512];
        pw2 = w4src[tid + 1024]; pw3 = w4src[tid + 1536];
    }
    __syncthreads();

    // ---------------- Phase E ----------------
    int cgi = tid & 31, es = tid >> 5;    // channel group; edges es*2+j
    f32x4 w0  = reinterpret_cast<const f32x4*>(w3r)[cgi];
    f32x4 w1  = reinterpret_cast<const f32x4*>(w3r)[32 + cgi];
    f32x4 w2  = reinterpret_cast<const f32x4*>(w3r)[64 + cgi];
    f32x4 w3v = reinterpret_cast<const f32x4*>(w3r)[96 + cgi];
    f32x4 gv[2], acc[2];
    #pragma unroll
    for (int j = 0; j < 2; ++j) {
        float4 e4 = efS[es * 2 + j];
        f32x4 g = w3v * splat4(e4.w);
        g = __builtin_elementwise_fma(splat4(e4.z), w2, g);
        g = __builtin_elementwise_fma(splat4(e4.y), w1, g);
        g = __builtin_elementwise_fma(splat4(e4.x), w0, g);
        gv[j] = g;
        acc[j] = splat4(0.f);
    }
    const f32x4* base4 = reinterpret_cast<const f32x4*>(baseS);
    const f32x4 zero = splat4(0.f);
    for (int beta = 0; beta < bl; ++beta) {
        f32x4 bs = base4[beta * 32 + cgi];
        float2 tv = *reinterpret_cast<const float2*>(tS + beta * 32 + es * 2);
        acc[0] += __builtin_elementwise_max(
            __builtin_elementwise_fma(splat4(tv.x), gv[0], bs), zero);
        acc[1] += __builtin_elementwise_max(
            __builtin_elementwise_fma(splat4(tv.y), gv[1], bs), zero);
    }
    if (bl < NBETA) {
        f32x4 bp = base4[bl * 32 + cgi];              // padded row == base_pad
        f32x4 r = __builtin_elementwise_max(bp, zero);
        f32x4 fcv = splat4((float)(NBETA - bl));
        acc[0] = __builtin_elementwise_fma(fcv, r, acc[0]);
        acc[1] = __builtin_elementwise_fma(fcv, r, acc[1]);
    }
    __syncthreads();   // S1: baseS/tS/efS/w3r dead

    // A-tile (bf16, XOR-swizzled) into io0; commit W4; prefetch W5
    #pragma unroll
    for (int j = 0; j < 2; ++j) {
        int rl = es * 2 + j;
        int byte = rl * 256 + ((cgi * 8) ^ ((rl & 7) << 4));
        ushort4 u;
        u.x = f2bf(acc[j].x); u.y = f2bf(acc[j].y);
        u.z = f2bf(acc[j].z); u.w = f2bf(acc[j].w);
        *reinterpret_cast<ushort4*>(io0 + byte) = u;
    }
    float4* wd = reinterpret_cast<float4*>(wS);
    wd[tid] = pw0; wd[tid + 512] = pw1; wd[tid + 1024] = pw2; wd[tid + 1536] = pw3;
    pw0 = w5src[tid];        pw1 = w5src[tid + 512];
    pw2 = w5src[tid + 1024]; pw3 = w5src[tid + 1536];
    __syncthreads();   // S2: A + W4 visible

    // ---------------- Phase F: 3-layer bf16 MFMA GEMM (32x128 @ 128x128) ---
    int l = tid & 63, wid = tid >> 6;
    int wm = wid & 1, wn = wid >> 1;      // 2M x 4N waves over 32x128
    const int lrow = l & 15;
    const int kbl = (l >> 4) * 16;        // byte offset of lane's 8 bf16

    auto layerc = [&](const char* ioIn, char* ioOut, const float* bias,
                      float bscale, bool doRelu, bool final_) {
        f32x4 facc[2];
        facc[0] = splat4(0.f); facc[1] = splat4(0.f);
        int rowA = wm * 16 + lrow;
        #pragma unroll
        for (int ks = 0; ks < 4; ++ks) {
            int kbyte = ks * 64 + kbl;
            short8 a = *reinterpret_cast<const short8*>(
                ioIn + rowA * 256 + (kbyte ^ ((rowA & 7) << 4)));
            #pragma unroll
            for (int nf = 0; nf < 2; ++nf) {
                int col = wn * 32 + nf * 16 + lrow;
                short8 bf = *reinterpret_cast<const short8*>(
                    wS + col * 256 + (kbyte ^ ((col & 7) << 4)));
                facc[nf] = __builtin_amdgcn_mfma_f32_16x16x32_bf16(a, bf, facc[nf], 0, 0, 0);
            }
        }
        #pragma unroll
        for (int nf = 0; nf < 2; ++nf) {
            int colg = wn * 32 + nf * 16 + lrow;
            float bvv = bias[colg];
            #pragma unroll
            for (int r = 0; r < 4; ++r) {
                int row = wm * 16 + (l >> 4) * 4 + r;
                float v = fmaf(bscale, bvv, facc[nf][r]);
                if (doRelu) v = fmaxf(v, 0.f);
                if (!final_) {
                    *reinterpret_cast<unsigned short*>(
                        ioOut + row * 256 + ((colg * 2) ^ ((row & 7) << 4))) = f2bf(v);
                } else {
                    int eg = e0 + row;
                    float vv = (eg >= el) ? 0.f : v;
                    out[(size_t)(b * NE + eg) * NHID + colg] = vv;
                }
            }
        }
    };

    layerc(io0, io1, b4, 64.f, false, false);      // h = hacc@W4 + 64*b4
    __syncthreads();   // S3: W4/io0 reads done
    wd[tid] = pw0; wd[tid + 512] = pw1; wd[tid + 1024] = pw2; wd[tid + 1536] = pw3;
    pw0 = w6src[tid];        pw1 = w6src[tid + 512];
    pw2 = w6src[tid + 1024]; pw3 = w6src[tid + 1536];
    __syncthreads();   // S4: W5 visible
    layerc(io1, io0, b5, 1.f, true, false);        // u = relu(h@W5 + b5)
    __syncthreads();   // S5: W5/io1 reads done
    wd[tid] = pw0; wd[tid + 512] = pw1; wd[tid + 1024] = pw2; wd[tid + 1536] = pw3;
    __syncthreads();   // S6: W6 visible
    layerc(io0, nullptr, b6, 1.f, false, true);    // out = u@W6 + b6 (masked)
}

extern "C" void kernel_launch(void* const* d_in, const int* in_sizes, int n_in,
                              void* d_out, int out_size, void* d_ws, size_t ws_size,
                              hipStream_t stream) {
    const float* x    = (const float*)d_in[0];
    const float* SCB  = (const float*)d_in[1];
    const int*   ei   = (const int*)d_in[2];
    const int*   elen = (const int*)d_in[3];
    const int*   blen = (const int*)d_in[4];
    const float* W1 = (const float*)d_in[5];  const float* b1 = (const float*)d_in[6];
    const float* W2 = (const float*)d_in[7];  const float* b2 = (const float*)d_in[8];
    const float* W3 = (const float*)d_in[9];  const float* b3 = (const float*)d_in[10];
    const float* W4 = (const float*)d_in[11]; const float* b4 = (const float*)d_in[12];
    const float* W5 = (const float*)d_in[13]; const float* b5 = (const float*)d_in[14];
    const float* W6 = (const float*)d_in[15]; const float* b6 = (const float*)d_in[16];
    float* out = (float*)d_out;

    float* ws = (float*)d_ws;
    float* base = ws;                                                   // 131072 f
    unsigned short* wsT = (unsigned short*)(base + NB * NBETA * NHID);  // 49152 bf16
    unsigned int* ctr = (unsigned int*)(wsT + 49152);                   // 4 B

    hipMemsetAsync(ctr, 0, 4, stream);     // reset barrier counter (capturable)
    hipLaunchKernelGGL(k_all, dim3(GRID), dim3(512), 0, stream,
                       x, ei, SCB, elen, blen, W1, b1, W2, b2, W3, b3,
                       W4, b4, W5, b5, W6, b6, base, wsT, ctr, out);
}

// Round 6
// 88.372 us; speedup vs baseline: 1.5494x; 1.5494x over previous
//
#include <hip/hip_runtime.h>
#include <hip/hip_bf16.h>

#define NB   16     // B
#define NN   512    // MAX_N
#define NE   1024   // MAX_E
#define NBETA 64    // MAX_BETA
#define NHID 128

typedef __attribute__((ext_vector_type(8))) short short8;
typedef __attribute__((ext_vector_type(4))) float f32x4;

static __device__ __forceinline__ unsigned short f2bf(float f) {
    unsigned u = __float_as_uint(f);
    return (unsigned short)((u + 0x7fffu + ((u >> 16) & 1u)) >> 16);   // RNE
}
static __device__ __forceinline__ unsigned packbf2(float lo, float hi) {
    return (unsigned)f2bf(lo) | ((unsigned)f2bf(hi) << 16);
}
static __device__ __forceinline__ f32x4 splat4(float v) {
    f32x4 r; r.x = v; r.y = v; r.z = v; r.w = v; return r;
}

// ---------------------------------------------------------------------------
// ONE regular kernel, 256 blocks x 512 thr, 64 KB LDS, zero inter-block deps.
// Block (b = bid&15, tile = bid>>4) owns 64 edges [e0, e0+64).
//   A : stage efAT (all-edge feats, SoA), tSa (|SCB| 64-edge tile), w3r,
//       W2 bf16 B-tile (inline transpose+swizzle convert)
//   B : s[beta][4] = masked sum over ALL edges (redundant per block; SCB slice
//       is L2-resident) ; 8 threads/beta + shfl reduce
//   C : h1 = relu(s@W1+b1) (VALU, fp32) -> bf16 A-tile ; stage W3 B-tile
//   D : emb-MFMA (h1a @ w2b + b2) -> bf16 A-tile
//   E2: base-MFMA (emba @ w3b + b3) -> f32 baseS
//   Phase E / A-tile / 3-layer MFMA phase F: lifted verbatim from the
//   verified R0/R4 kernels; W4/5/6 converted from global inline per layer.
// No workspace use at all.
// ---------------------------------------------------------------------------
__global__ __launch_bounds__(512) void k_one(
        const float* __restrict__ x, const int* __restrict__ ei,
        const float* __restrict__ SCB,
        const int* __restrict__ elen, const int* __restrict__ blen,
        const float* __restrict__ W1, const float* __restrict__ b1,
        const float* __restrict__ W2, const float* __restrict__ b2,
        const float* __restrict__ W3, const float* __restrict__ b3,
        const float* __restrict__ W4, const float* __restrict__ b4,
        const float* __restrict__ W5, const float* __restrict__ b5,
        const float* __restrict__ W6, const float* __restrict__ b6,
        float* __restrict__ out) {
    __shared__ __align__(16) char lds[65536];
    char* r0 = lds;
    char* r1 = lds + 32768;
    int bid = blockIdx.x, tid = threadIdx.x;
    int b = bid & 15;
    int e0 = (bid >> 4) * 64;
    int el = elen[b];
    if (e0 >= el) {                      // fully-padded tile: zero 64x128 out
        float4 z; z.x = 0.f; z.y = 0.f; z.z = 0.f; z.w = 0.f;
        float4* o4 = reinterpret_cast<float4*>(out) + (size_t)(b * NE + e0) * 32;
        #pragma unroll
        for (int q = 0; q < 4; ++q) o4[tid + 512 * q] = z;
        return;
    }
    int bl = blen[b];

    // LDS overlays (lifetimes commented)
    float*  efAT = reinterpret_cast<float*>(r1);            // [4][1024] 16K: A..B
    float*  w3r  = reinterpret_cast<float*>(r1 + 16384);    // 512 f 2K: A..A2
    f32x4*  sS4  = reinterpret_cast<f32x4*>(r1 + 18432);    // 64 vec 1K: B..C
    float4* tS4  = reinterpret_cast<float4*>(r0);           // [64][16] 16K: A..E
    char* w2b  = r0 + 16384;   // 8K bf16 B-tile  : A..D
    char* h1a  = r0 + 24576;   // 8K bf16 A-tile  : C..D
    char* w3b  = r1;           // 16K bf16 B-tile : C..E2   (over efAT)
    char* emba = r0 + 16384;   // 8K bf16 A-tile  : D..E2   (over w2b)
    float* baseS = reinterpret_cast<float*>(r1);  // 32K f32: E2..phaseE (over w3b)
    char* io0 = r0;            // 16K: phaseE.. (over tS4)
    char* io1 = r0 + 16384;    // 16K
    char* wS  = r1;            // 32K: phaseF (over baseS)

    // ---------------- A: stage ----------------
    {
        const int* eib = ei + b * 2 * NE;
        const float* xb = x + b * NN * 2;
        for (int e = tid; e < NE; e += 512) {
            int i0 = eib[e], i1 = eib[NE + e];
            float2 v0 = *reinterpret_cast<const float2*>(xb + 2 * i0);
            float2 v1 = *reinterpret_cast<const float2*>(xb + 2 * i1);
            efAT[e] = v0.x; efAT[1024 + e] = v0.y;
            efAT[2048 + e] = v1.x; efAT[3072 + e] = v1.y;
        }
        const float4* scb4 = reinterpret_cast<const float4*>(
            SCB + (size_t)(b * NBETA) * NE);
        for (int i = tid; i < 1024; i += 512) {
            int row = i >> 4, c4 = i & 15;
            float4 v = scb4[row * 256 + (e0 >> 2) + c4];
            v.x = fabsf(v.x); v.y = fabsf(v.y); v.z = fabsf(v.z); v.w = fabsf(v.w);
            tS4[i] = v;
        }
        w3r[tid] = W3[64 * NHID + tid];          // W3 rows 64..67
        {   // W2 -> w2b ([64 n][64 k] bf16, swizzled); 1 cell/thread
            int c = tid >> 4, n4 = tid & 15;     // k-pair, n-float4
            float4 lo = *reinterpret_cast<const float4*>(W2 + (2 * c) * 64 + n4 * 4);
            float4 hi = *reinterpret_cast<const float4*>(W2 + (2 * c + 1) * 64 + n4 * 4);
            #pragma unroll
            for (int m = 0; m < 4; ++m) {
                int n = n4 * 4 + m;
                *reinterpret_cast<unsigned*>(
                    w2b + n * 128 + ((4 * c) ^ ((n & 7) << 4))) =
                    packbf2(((const float*)&lo)[m], ((const float*)&hi)[m]);
            }
        }
    }
    __syncthreads();

    // ---------------- A2: per-thread phase-E operands (gv) -----------------
    int cg = tid & 31, slot = tid >> 5;          // channel f32x4, edge group
    f32x4 gv[4];
    {
        f32x4 w0  = reinterpret_cast<const f32x4*>(w3r)[cg];
        f32x4 w1v = reinterpret_cast<const f32x4*>(w3r)[32 + cg];
        f32x4 w2v = reinterpret_cast<const f32x4*>(w3r)[64 + cg];
        f32x4 w3v = reinterpret_cast<const f32x4*>(w3r)[96 + cg];
        #pragma unroll
        for (int j = 0; j < 4; ++j) {
            int e = e0 + slot * 4 + j;
            f32x4 g = w3v * splat4(efAT[3072 + e]);
            g = __builtin_elementwise_fma(splat4(efAT[2048 + e]), w2v, g);
            g = __builtin_elementwise_fma(splat4(efAT[1024 + e]), w1v, g);
            g = __builtin_elementwise_fma(splat4(efAT[e]), w0, g);
            gv[j] = g;
        }
    }

    // ---------------- B: s-compute (full edge sum, redundant) --------------
    {
        int beta = tid >> 3, j = tid & 7;
        f32x4 sacc = splat4(0.f);
        if (beta < bl) {
            const float4* row4 = reinterpret_cast<const float4*>(
                SCB + (size_t)(b * NBETA + beta) * NE);
            for (int k = 0; k < 32; ++k) {
                int f = j + 8 * k, e = 4 * f;
                float4 c4 = row4[f];
                float m0 = (e     < el) ? fabsf(c4.x) : 0.f;
                float m1 = (e + 1 < el) ? fabsf(c4.y) : 0.f;
                float m2 = (e + 2 < el) ? fabsf(c4.z) : 0.f;
                float m3 = (e + 3 < el) ? fabsf(c4.w) : 0.f;
                #pragma unroll
                for (int i = 0; i < 4; ++i) {
                    const float* efi = efAT + i * 1024 + e;
                    float v = sacc[i];
                    v = fmaf(m0, efi[0], v);
                    v = fmaf(m1, efi[1], v);
                    v = fmaf(m2, efi[2], v);
                    v = fmaf(m3, efi[3], v);
                    sacc[i] = v;
                }
            }
        }
        #pragma unroll
        for (int off = 4; off > 0; off >>= 1) {
            sacc[0] += __shfl_down(sacc[0], off);
            sacc[1] += __shfl_down(sacc[1], off);
            sacc[2] += __shfl_down(sacc[2], off);
            sacc[3] += __shfl_down(sacc[3], off);
        }
        if (j == 0) sS4[beta] = sacc;
    }
    __syncthreads();

    // ---------------- C: h1 (fp32 VALU) -> h1a ; stage W3 -> w3b -----------
    {
        int beta = tid >> 3, c0 = (tid & 7) * 8;
        f32x4 sv = sS4[beta];
        float h[8];
        #pragma unroll
        for (int cc = 0; cc < 8; ++cc) {
            int c = c0 + cc;
            float v = b1[c];
            v = fmaf(sv[0], W1[c], v);
            v = fmaf(sv[1], W1[64 + c], v);
            v = fmaf(sv[2], W1[128 + c], v);
            v = fmaf(sv[3], W1[192 + c], v);
            h[cc] = fmaxf(v, 0.f);
        }
        #pragma unroll
        for (int p = 0; p < 4; ++p) {
            int c = c0 + 2 * p;
            *reinterpret_cast<unsigned*>(
                h1a + beta * 128 + ((2 * c) ^ ((beta & 7) << 4))) =
                packbf2(h[2 * p], h[2 * p + 1]);
        }
        // W3 rows 0..63 -> w3b ([128 n][64 k] bf16, swizzled); 2 cells/thread
        int cw = tid >> 5, n4 = tid & 31;
        #pragma unroll
        for (int q = 0; q < 2; ++q) {
            int c = cw + 16 * q;
            float4 lo = *reinterpret_cast<const float4*>(W3 + (2 * c) * NHID + n4 * 4);
            float4 hi = *reinterpret_cast<const float4*>(W3 + (2 * c + 1) * NHID + n4 * 4);
            #pragma unroll
            for (int m = 0; m < 4; ++m) {
                int n = n4 * 4 + m;
                *reinterpret_cast<unsigned*>(
                    w3b + n * 128 + ((4 * c) ^ ((n & 7) << 4))) =
                    packbf2(((const float*)&lo)[m], ((const float*)&hi)[m]);
            }
        }
    }
    __syncthreads();

    int l = tid & 63, wid = tid >> 6;
    const int lrow = l & 15;
    const int kbl = (l >> 4) * 16;

    // ---------------- D: emb = h1a @ w2b + b2 -> emba ----------------------
    {
        int wm = wid & 3, wn = wid >> 2;         // 4M x 2N over 64x64
        f32x4 ef[2];
        ef[0] = splat4(0.f); ef[1] = splat4(0.f);
        int rowA = wm * 16 + lrow;
        #pragma unroll
        for (int ks = 0; ks < 2; ++ks) {
            int kbyte = ks * 64 + kbl;
            short8 a = *reinterpret_cast<const short8*>(
                h1a + rowA * 128 + (kbyte ^ ((rowA & 7) << 4)));
            #pragma unroll
            for (int nf = 0; nf < 2; ++nf) {
                int col = wn * 32 + nf * 16 + lrow;
                short8 bf = *reinterpret_cast<const short8*>(
                    w2b + col * 128 + (kbyte ^ ((col & 7) << 4)));
                ef[nf] = __builtin_amdgcn_mfma_f32_16x16x32_bf16(a, bf, ef[nf], 0, 0, 0);
            }
        }
        __syncthreads();                         // w2b reads done -> emba writable
        #pragma unroll
        for (int nf = 0; nf < 2; ++nf) {
            int colg = wn * 32 + nf * 16 + lrow;
            float bv = b2[colg];
            #pragma unroll
            for (int r = 0; r < 4; ++r) {
                int beta = wm * 16 + (l >> 4) * 4 + r;
                *reinterpret_cast<unsigned short*>(
                    emba + beta * 128 + ((2 * colg) ^ ((beta & 7) << 4))) =
                    f2bf(ef[nf][r] + bv);
            }
        }
    }
    __syncthreads();

    // ---------------- E2: base = emba @ w3b + b3 -> baseS (f32) ------------
    {
        int wm = wid & 3, wn = wid >> 2;         // 4M x 2N over 64x128
        f32x4 bf4[4];
        #pragma unroll
        for (int nf = 0; nf < 4; ++nf) bf4[nf] = splat4(0.f);
        int rowA = wm * 16 + lrow;
        #pragma unroll
        for (int ks = 0; ks < 2; ++ks) {
            int kbyte = ks * 64 + kbl;
            short8 a = *reinterpret_cast<const short8*>(
                emba + rowA * 128 + (kbyte ^ ((rowA & 7) << 4)));
            #pragma unroll
            for (int nf = 0; nf < 4; ++nf) {
                int col = wn * 64 + nf * 16 + lrow;
                short8 bfr = *reinterpret_cast<const short8*>(
                    w3b + col * 128 + (kbyte ^ ((col & 7) << 4)));
                bf4[nf] = __builtin_amdgcn_mfma_f32_16x16x32_bf16(a, bfr, bf4[nf], 0, 0, 0);
            }
        }
        __syncthreads();                         // w3b reads done -> baseS writable
        #pragma unroll
        for (int nf = 0; nf < 4; ++nf) {
            int colg = wn * 64 + nf * 16 + lrow;
            float bv = b3[colg];
            #pragma unroll
            for (int r = 0; r < 4; ++r) {
                int beta = wm * 16 + (l >> 4) * 4 + r;
                baseS[beta * NHID + colg] = bf4[nf][r] + bv;
            }
        }
    }
    __syncthreads();

    // ---------------- Phase E (R0-verified) --------------------------------
    f32x4 acc[4];
    #pragma unroll
    for (int j = 0; j < 4; ++j) acc[j] = splat4(0.f);
    {
        const f32x4* base4 = reinterpret_cast<const f32x4*>(baseS);
        const f32x4 zero = splat4(0.f);
        for (int beta = 0; beta < bl; ++beta) {
            f32x4 bs = base4[beta * 32 + cg];
            float4 tv = tS4[beta * 16 + slot];
            acc[0] += __builtin_elementwise_max(
                __builtin_elementwise_fma(splat4(tv.x), gv[0], bs), zero);
            acc[1] += __builtin_elementwise_max(
                __builtin_elementwise_fma(splat4(tv.y), gv[1], bs), zero);
            acc[2] += __builtin_elementwise_max(
                __builtin_elementwise_fma(splat4(tv.z), gv[2], bs), zero);
            acc[3] += __builtin_elementwise_max(
                __builtin_elementwise_fma(splat4(tv.w), gv[3], bs), zero);
        }
        if (bl < NBETA) {
            f32x4 bp = base4[bl * 32 + cg];
            f32x4 r = __builtin_elementwise_max(bp, zero);
            f32x4 fcv = splat4((float)(NBETA - bl));
            #pragma unroll
            for (int j = 0; j < 4; ++j)
                acc[j] = __builtin_elementwise_fma(fcv, r, acc[j]);
        }
    }
    __syncthreads();   // S1: tS4 & baseS dead

    // A-tile (bf16 swizzled) -> io0 ; W4 convert -> wS
    #pragma unroll
    for (int j = 0; j < 4; ++j) {
        int rl = slot * 4 + j;
        int byte = rl * 256 + ((cg * 8) ^ ((rl & 7) << 4));
        ushort4 u;
        u.x = f2bf(acc[j].x); u.y = f2bf(acc[j].y);
        u.z = f2bf(acc[j].z); u.w = f2bf(acc[j].w);
        *reinterpret_cast<ushort4*>(io0 + byte) = u;
    }
    auto commitW = [&](const float* Wg) {        // [128 n][128 k] bf16 swizzled
        int c0 = tid >> 5, n4 = tid & 31;
        #pragma unroll
        for (int q = 0; q < 4; ++q) {
            int c = c0 + 16 * q;
            float4 lo = *reinterpret_cast<const float4*>(Wg + (2 * c) * NHID + n4 * 4);
            float4 hi = *reinterpret_cast<const float4*>(Wg + (2 * c + 1) * NHID + n4 * 4);
            #pragma unroll
            for (int m = 0; m < 4; ++m) {
                int n = n4 * 4 + m;
                *reinterpret_cast<unsigned*>(
                    wS + n * 256 + ((4 * c) ^ ((n & 7) << 4))) =
                    packbf2(((const float*)&lo)[m], ((const float*)&hi)[m]);
            }
        }
    };
    commitW(W4);
    __syncthreads();   // S2

    // ---------------- Phase F: 3-layer MFMA (R0-verified, M=64) ------------
    auto layerc = [&](const char* ioIn, char* ioOut, const float* bias,
                      float bscale, bool doRelu, bool final_) {
        int wm = wid & 3, wn = wid >> 2;         // 4M x 2N over 64x128
        f32x4 facc[4];
        #pragma unroll
        for (int nf = 0; nf < 4; ++nf) facc[nf] = splat4(0.f);
        int rowA = wm * 16 + lrow;
        #pragma unroll
        for (int ks = 0; ks < 4; ++ks) {
            int kbyte = ks * 64 + kbl;
            short8 a = *reinterpret_cast<const short8*>(
                ioIn + rowA * 256 + (kbyte ^ ((rowA & 7) << 4)));
            #pragma unroll
            for (int nf = 0; nf < 4; ++nf) {
                int col = wn * 64 + nf * 16 + lrow;
                short8 bfr = *reinterpret_cast<const short8*>(
                    wS + col * 256 + (kbyte ^ ((col & 7) << 4)));
                facc[nf] = __builtin_amdgcn_mfma_f32_16x16x32_bf16(a, bfr, facc[nf], 0, 0, 0);
            }
        }
        #pragma unroll
        for (int nf = 0; nf < 4; ++nf) {
            int colg = wn * 64 + nf * 16 + lrow;
            float bvv = bias[colg];
            #pragma unroll
            for (int r = 0; r < 4; ++r) {
                int row = wm * 16 + (l >> 4) * 4 + r;
                float v = fmaf(bscale, bvv, facc[nf][r]);
                if (doRelu) v = fmaxf(v, 0.f);
                if (!final_) {
                    *reinterpret_cast<unsigned short*>(
                        ioOut + row * 256 + ((colg * 2) ^ ((row & 7) << 4))) = f2bf(v);
                } else {
                    int eg = e0 + row;
                    float vv = (eg >= el) ? 0.f : v;
                    out[(size_t)(b * NE + eg) * NHID + colg] = vv;
                }
            }
        }
    };

    layerc(io0, io1, b4, 64.f, false, false);    // h = hacc@W4 + 64*b4
    __syncthreads();   // S3: W4/io0 reads done
    commitW(W5);
    __syncthreads();   // S4
    layerc(io1, io0, b5, 1.f, true, false);      // u = relu(h@W5 + b5)
    __syncthreads();   // S5: W5/io1 reads done
    commitW(W6);
    __syncthreads();   // S6
    layerc(io0, nullptr, b6, 1.f, false, true);  // out = u@W6 + b6 (masked)
}

extern "C" void kernel_launch(void* const* d_in, const int* in_sizes, int n_in,
                              void* d_out, int out_size, void* d_ws, size_t ws_size,
                              hipStream_t stream) {
    const float* x    = (const float*)d_in[0];
    const float* SCB  = (const float*)d_in[1];
    const int*   ei   = (const int*)d_in[2];
    const int*   elen = (const int*)d_in[3];
    const int*   blen = (const int*)d_in[4];
    const float* W1 = (const float*)d_in[5];  const float* b1 = (const float*)d_in[6];
    const float* W2 = (const float*)d_in[7];  const float* b2 = (const float*)d_in[8];
    const float* W3 = (const float*)d_in[9];  const float* b3 = (const float*)d_in[10];
    const float* W4 = (const float*)d_in[11]; const float* b4 = (const float*)d_in[12];
    const float* W5 = (const float*)d_in[13]; const float* b5 = (const float*)d_in[14];
    const float* W6 = (const float*)d_in[15]; const float* b6 = (const float*)d_in[16];
    float* out = (float*)d_out;

    hipLaunchKernelGGL(k_one, dim3(256), dim3(512), 0, stream,
                       x, ei, SCB, elen, blen, W1, b1, W2, b2, W3, b3,
                       W4, b4, W5, b5, W6, b6, out);
}

// Round 7
// 30.109 us; speedup vs baseline: 4.5475x; 2.9350x over previous
//
#include <hip/hip_runtime.h>
#include <hip/hip_bf16.h>

#define NB   16     // B
#define NN   512    // MAX_N
#define NE   1024   // MAX_E
#define NBETA 64    // MAX_BETA
#define NHID 128

typedef __attribute__((ext_vector_type(8))) short short8;
typedef __attribute__((ext_vector_type(4))) float f32x4;

static __device__ __forceinline__ unsigned short f2bf(float f) {
    unsigned u = __float_as_uint(f);
    return (unsigned short)((u + 0x7fffu + ((u >> 16) & 1u)) >> 16);   // RNE
}

static __device__ __forceinline__ f32x4 splat4(float v) {
    f32x4 r; r.x = v; r.y = v; r.z = v; r.w = v; return r;
}

// ---------------------------------------------------------------------------
// Two-dispatch structure (verified best: 26.96 us).
// Workspace (floats): base = NB*NBETA*128 (512 KB); wsT = 3*128*128 bf16 (96 KB)
// ---------------------------------------------------------------------------

// Kernel 1 (256 blocks x 512): four (b,beta) tasks/block (128 thr each,
//   wave-shfl butterfly reduce) -> base[]; plus 192 weight elems/block ->
//   bf16 transposed + XOR-swizzled wsT[].
__global__ __launch_bounds__(512) void k_base_wt(
        const float* __restrict__ x, const int* __restrict__ ei,
        const float* __restrict__ SCB,
        const int* __restrict__ elen, const int* __restrict__ blen,
        const float* __restrict__ W1, const float* __restrict__ b1,
        const float* __restrict__ W2, const float* __restrict__ b2,
        const float* __restrict__ W3, const float* __restrict__ b3,
        const float* __restrict__ W4, const float* __restrict__ W5,
        const float* __restrict__ W6,
        float* __restrict__ base, unsigned short* __restrict__ wsT) {
    __shared__ float part[32];        // [8 waves][4]
    __shared__ float h1s[4][64];
    __shared__ float embs[4][64];
    int bid = blockIdx.x, tid = threadIdx.x;

    // --- weight transform: 192 elems/block (256*192 = 49152 total) ---
    if (tid < 192) {
        int j = bid * 192 + tid;
        int w = j >> 14, rem = j & 16383;
        int k = rem & 127, n = rem >> 7;
        const float* W = (w == 0) ? W4 : ((w == 1) ? W5 : W6);
        float v = W[k * NHID + n];
        int byte = n * 256 + ((2 * k) ^ ((n & 7) << 4));
        *reinterpret_cast<unsigned short*>(
            reinterpret_cast<char*>(wsT) + (size_t)w * 32768 + byte) = f2bf(v);
    }

    // --- four (b,beta) tasks per block ---
    int hf = tid >> 7, t = tid & 127;             // task, lane-in-task
    int bb = bid * 4 + hf;                        // 0..1023
    int b = bb >> 6, beta = bb & 63;
    int el = elen[b], bl = blen[b];
    float a0 = 0, a1 = 0, a2 = 0, a3 = 0;
    if (beta < bl) {
        const float* row = SCB + (size_t)bb * NE;
        const int* eis = ei + b * 2 * NE;
        const float* xb = x + b * NN * 2;
        for (int e = t; e < el; e += 128) {
            float tt = fabsf(row[e]);
            int s0 = eis[e], s1 = eis[NE + e];
            float2 v0 = *reinterpret_cast<const float2*>(xb + 2 * s0);
            float2 v1 = *reinterpret_cast<const float2*>(xb + 2 * s1);
            a0 = fmaf(tt, v0.x, a0);
            a1 = fmaf(tt, v0.y, a1);
            a2 = fmaf(tt, v1.x, a2);
            a3 = fmaf(tt, v1.y, a3);
        }
    }
    #pragma unroll
    for (int off = 32; off > 0; off >>= 1) {      // wave64 butterfly
        a0 += __shfl_down(a0, off);
        a1 += __shfl_down(a1, off);
        a2 += __shfl_down(a2, off);
        a3 += __shfl_down(a3, off);
    }
    if ((tid & 63) == 0) {
        int w8 = tid >> 6;
        part[w8 * 4 + 0] = a0; part[w8 * 4 + 1] = a1;
        part[w8 * 4 + 2] = a2; part[w8 * 4 + 3] = a3;
    }
    __syncthreads();
    if (t < 64) {
        float v = b1[t];
        #pragma unroll
        for (int i = 0; i < 4; ++i) {
            float si = part[(2 * hf) * 4 + i] + part[(2 * hf + 1) * 4 + i];
            v = fmaf(si, W1[i * 64 + t], v);
        }
        h1s[hf][t] = fmaxf(v, 0.f);
    }
    __syncthreads();
    if (t < 64) {
        float v = b2[t];
        #pragma unroll 8
        for (int k = 0; k < 64; ++k) v = fmaf(h1s[hf][k], W2[k * 64 + t], v);
        embs[hf][t] = v;
    }
    __syncthreads();
    {
        float v = b3[t];
        #pragma unroll 8
        for (int k = 0; k < 64; ++k) v = fmaf(embs[hf][k], W3[k * NHID + t], v);
        base[(size_t)bb * NHID + t] = v;
    }
}

// Kernel 2 (512 blocks x 512): per 32-edge tile.  b = bid & 15 interleave.
//   Padded tiles (e0 >= el) zero-store and exit.  W4/W5/W6 register-
//   prefetched, committed to LDS post-barrier.  Stage loops bounded by bl
//   (phase E only reads base/tS rows 0..bl).
__global__ __launch_bounds__(512) void k_fused(
        const float* __restrict__ x, const int* __restrict__ ei,
        const float* __restrict__ SCB,
        const int* __restrict__ elen, const int* __restrict__ blen,
        const float* __restrict__ W3,
        const float* __restrict__ base, const unsigned short* __restrict__ wsT,
        const float* __restrict__ b4, const float* __restrict__ b5,
        const float* __restrict__ b6,
        float* __restrict__ out) {
    int bid = blockIdx.x, tid = threadIdx.x;
    int b = bid & 15;
    int e0 = (bid >> 4) * 32;
    int el = elen[b];
    if (e0 >= el) {                       // fully-padded tile: zero and leave
        float4 z; z.x = 0.f; z.y = 0.f; z.z = 0.f; z.w = 0.f;
        float4* o4 = reinterpret_cast<float4*>(out) + (size_t)(b * NE + e0) * (NHID / 4);
        o4[tid] = z;
        o4[tid + 512] = z;
        return;
    }
    int bl = blen[b];
    int nrows = (bl < NBETA) ? bl + 1 : NBETA;    // rows 0..bl touched in E

    __shared__ __align__(16) char lds[65536];
    float* baseS = reinterpret_cast<float*>(lds);             // 32K, dead after E
    char*  wS    = lds + 32768;                               // 32K
    float4* efS  = reinterpret_cast<float4*>(wS);             // 512 B
    float* w3r   = reinterpret_cast<float*>(wS + 512);        // 2 K
    float* tS    = reinterpret_cast<float*>(wS + 8192);       // 8 K [beta][32]
    char* io0 = lds;                                          // 8K A-tile / L5 out
    char* io1 = lds + 8192;                                   // 8K L4 out

    const float4* w4src = reinterpret_cast<const float4*>(wsT);
    const float4* w5src = reinterpret_cast<const float4*>(
        reinterpret_cast<const char*>(wsT) + 32768);
    const float4* w6src = reinterpret_cast<const float4*>(
        reinterpret_cast<const char*>(wsT) + 65536);
    float4 pw0, pw1, pw2, pw3;            // in-flight weight tile

    {   // stage (base rows 0..bl, |SCB| rows 0..bl-1, edge feats, W3 rows
        // 64..67) + W4 prefetch
        const float4* bsrc = reinterpret_cast<const float4*>(base + (size_t)b * NBETA * NHID);
        float4* bd = reinterpret_cast<float4*>(baseS);
        int nb4 = nrows * 32;                       // float4s of baseS needed
        for (int i = tid; i < nb4; i += 512) bd[i] = bsrc[i];
        {
            int row = tid >> 3, c4 = tid & 7;
            if (row < bl) {
                float4 v = *reinterpret_cast<const float4*>(
                    SCB + (size_t)(b * NBETA + row) * NE + e0 + c4 * 4);
                v.x = fabsf(v.x); v.y = fabsf(v.y); v.z = fabsf(v.z); v.w = fabsf(v.w);
                reinterpret_cast<float4*>(tS)[tid] = v;
            }
        }
        if (tid < 64) {
            int e = tid >> 1, hf = tid & 1;
            int idx = ei[b * 2 * NE + hf * NE + e0 + e];
            float2 v2 = *reinterpret_cast<const float2*>(x + b * NN * 2 + idx * 2);
            reinterpret_cast<float2*>(&efS[e])[hf] = v2;
        }
        w3r[tid] = W3[64 * NHID + tid];
        pw0 = w4src[tid];        pw1 = w4src[tid + 512];     // issued last ->
        pw2 = w4src[tid + 1024]; pw3 = w4src[tid + 1536];    // stay in flight
    }
    __syncthreads();

    // ---------------- Phase E ----------------
    int cg = tid & 31, es = tid >> 5;       // cg: f32x4 channel group; edges es*2+j
    f32x4 w0  = reinterpret_cast<const f32x4*>(w3r)[cg];
    f32x4 w1  = reinterpret_cast<const f32x4*>(w3r)[32 + cg];
    f32x4 w2  = reinterpret_cast<const f32x4*>(w3r)[64 + cg];
    f32x4 w3v = reinterpret_cast<const f32x4*>(w3r)[96 + cg];
    f32x4 gv[2], acc[2];
    #pragma unroll
    for (int j = 0; j < 2; ++j) {
        float4 e4 = efS[es * 2 + j];
        f32x4 g = w3v * splat4(e4.w);
        g = __builtin_elementwise_fma(splat4(e4.z), w2, g);
        g = __builtin_elementwise_fma(splat4(e4.y), w1, g);
        g = __builtin_elementwise_fma(splat4(e4.x), w0, g);
        gv[j] = g;
        acc[j] = splat4(0.f);
    }
    const f32x4* base4 = reinterpret_cast<const f32x4*>(baseS);
    const f32x4 zero = splat4(0.f);
    for (int beta = 0; beta < bl; ++beta) {
        f32x4 bs = base4[beta * 32 + cg];
        float2 tv = *reinterpret_cast<const float2*>(tS + beta * 32 + es * 2);
        acc[0] += __builtin_elementwise_max(
            __builtin_elementwise_fma(splat4(tv.x), gv[0], bs), zero);
        acc[1] += __builtin_elementwise_max(
            __builtin_elementwise_fma(splat4(tv.y), gv[1], bs), zero);
    }
    if (bl < NBETA) {
        f32x4 bp = base4[bl * 32 + cg];              // any padded row == base_pad
        f32x4 r = __builtin_elementwise_max(bp, zero);
        f32x4 fcv = splat4((float)(NBETA - bl));
        acc[0] = __builtin_elementwise_fma(fcv, r, acc[0]);
        acc[1] = __builtin_elementwise_fma(fcv, r, acc[1]);
    }
    __syncthreads();   // S1: baseS/tS/efS/w3r all dead

    // A-tile (bf16, XOR-swizzled) into io0; commit W4; prefetch W5
    #pragma unroll
    for (int j = 0; j < 2; ++j) {
        int rl = es * 2 + j;
        int byte = rl * 256 + ((cg * 8) ^ ((rl & 7) << 4));
        ushort4 u;
        u.x = f2bf(acc[j].x); u.y = f2bf(acc[j].y);
        u.z = f2bf(acc[j].z); u.w = f2bf(acc[j].w);
        *reinterpret_cast<ushort4*>(io0 + byte) = u;
    }
    float4* wd = reinterpret_cast<float4*>(wS);
    wd[tid] = pw0; wd[tid + 512] = pw1; wd[tid + 1024] = pw2; wd[tid + 1536] = pw3;
    pw0 = w5src[tid];        pw1 = w5src[tid + 512];
    pw2 = w5src[tid + 1024]; pw3 = w5src[tid + 1536];
    __syncthreads();   // S2: A + W4 visible

    // ---------------- Phase F: 3-layer bf16 MFMA GEMM (32x128 @ 128x128) ----
    int l = tid & 63, wid = tid >> 6;
    int wm = wid & 1, wn = wid >> 1;           // 2M x 4N waves over 32x128
    const int lrow = l & 15;
    const int kbl = (l >> 4) * 16;             // byte offset of lane's 8 bf16

    auto layerc = [&](const char* ioIn, char* ioOut, const float* bias,
                      float bscale, bool doRelu, bool final_) {
        f32x4 facc[2];
        facc[0] = splat4(0.f); facc[1] = splat4(0.f);
        int rowA = wm * 16 + lrow;
        #pragma unroll
        for (int ks = 0; ks < 4; ++ks) {
            int kbyte = ks * 64 + kbl;
            short8 a = *reinterpret_cast<const short8*>(
                ioIn + rowA * 256 + (kbyte ^ ((rowA & 7) << 4)));
            #pragma unroll
            for (int nf = 0; nf < 2; ++nf) {
                int col = wn * 32 + nf * 16 + lrow;
                short8 bf = *reinterpret_cast<const short8*>(
                    wS + col * 256 + (kbyte ^ ((col & 7) << 4)));
                facc[nf] = __builtin_amdgcn_mfma_f32_16x16x32_bf16(a, bf, facc[nf], 0, 0, 0);
            }
        }
        #pragma unroll
        for (int nf = 0; nf < 2; ++nf) {
            int colg = wn * 32 + nf * 16 + lrow;
            float bvv = bias[colg];
            #pragma unroll
            for (int r = 0; r < 4; ++r) {
                int row = wm * 16 + (l >> 4) * 4 + r;
                float v = fmaf(bscale, bvv, facc[nf][r]);
                if (doRelu) v = fmaxf(v, 0.f);
                if (!final_) {
                    *reinterpret_cast<unsigned short*>(
                        ioOut + row * 256 + ((colg * 2) ^ ((row & 7) << 4))) = f2bf(v);
                } else {
                    int eg = e0 + row;
                    float vv = (eg >= el) ? 0.f : v;
                    out[(size_t)(b * NE + eg) * NHID + colg] = vv;
                }
            }
        }
    };

    layerc(io0, io1, b4, 64.f, false, false);      // h = hacc@W4 + 64*b4
    __syncthreads();   // S3: W4/io0 reads done
    wd[tid] = pw0; wd[tid + 512] = pw1; wd[tid + 1024] = pw2; wd[tid + 1536] = pw3;
    pw0 = w6src[tid];        pw1 = w6src[tid + 512];
    pw2 = w6src[tid + 1024]; pw3 = w6src[tid + 1536];
    __syncthreads();   // S4: W5 visible
    layerc(io1, io0, b5, 1.f, true, false);        // u = relu(h@W5 + b5)
    __syncthreads();   // S5: W5/io1 reads done
    wd[tid] = pw0; wd[tid + 512] = pw1; wd[tid + 1024] = pw2; wd[tid + 1536] = pw3;
    __syncthreads();   // S6: W6 visible
    layerc(io0, nullptr, b6, 1.f, false, true);    // out = u@W6 + b6 (masked)
}

extern "C" void kernel_launch(void* const* d_in, const int* in_sizes, int n_in,
                              void* d_out, int out_size, void* d_ws, size_t ws_size,
                              hipStream_t stream) {
    const float* x    = (const float*)d_in[0];
    const float* SCB  = (const float*)d_in[1];
    const int*   ei   = (const int*)d_in[2];
    const int*   elen = (const int*)d_in[3];
    const int*   blen = (const int*)d_in[4];
    const float* W1 = (const float*)d_in[5];  const float* b1 = (const float*)d_in[6];
    const float* W2 = (const float*)d_in[7];  const float* b2 = (const float*)d_in[8];
    const float* W3 = (const float*)d_in[9];  const float* b3 = (const float*)d_in[10];
    const float* W4 = (const float*)d_in[11]; const float* b4 = (const float*)d_in[12];
    const float* W5 = (const float*)d_in[13]; const float* b5 = (const float*)d_in[14];
    const float* W6 = (const float*)d_in[15]; const float* b6 = (const float*)d_in[16];
    float* out = (float*)d_out;

    float* ws = (float*)d_ws;
    float* base = ws;                                                   // 131072 f
    unsigned short* wsT = (unsigned short*)(base + NB * NBETA * NHID);  // 49152 bf16

    hipLaunchKernelGGL(k_base_wt, dim3(256), dim3(512), 0, stream,
                       x, ei, SCB, elen, blen, W1, b1, W2, b2, W3, b3, W4, W5, W6, base, wsT);
    hipLaunchKernelGGL(k_fused, dim3(512), dim3(512), 0, stream,
                       x, ei, SCB, elen, blen, W3, base, wsT, b4, b5, b6, out);
}

// Round 8
// 29.646 us; speedup vs baseline: 4.6186x; 1.0156x over previous
//
#include <hip/hip_runtime.h>
#include <hip/hip_bf16.h>

#define NB   16     // B
#define NN   512    // MAX_N
#define NE   1024   // MAX_E
#define NBETA 64    // MAX_BETA
#define NHID 128

typedef __attribute__((ext_vector_type(8))) short short8;
typedef __attribute__((ext_vector_type(4))) float f32x4;

static __device__ __forceinline__ unsigned short f2bf(float f) {
    unsigned u = __float_as_uint(f);
    return (unsigned short)((u + 0x7fffu + ((u >> 16) & 1u)) >> 16);   // RNE
}

static __device__ __forceinline__ f32x4 splat4(float v) {
    f32x4 r; r.x = v; r.y = v; r.z = v; r.w = v; return r;
}

// ---------------------------------------------------------------------------
// Two-dispatch structure (verified best: 26.96 us).
// Workspace (floats): base = NB*NBETA*128 (512 KB); wsT = 3*128*128 bf16 (96 KB)
// ---------------------------------------------------------------------------

// Kernel 1 (256 blocks x 512) — R4-verified verbatim.
__global__ __launch_bounds__(512) void k_base_wt(
        const float* __restrict__ x, const int* __restrict__ ei,
        const float* __restrict__ SCB,
        const int* __restrict__ elen, const int* __restrict__ blen,
        const float* __restrict__ W1, const float* __restrict__ b1,
        const float* __restrict__ W2, const float* __restrict__ b2,
        const float* __restrict__ W3, const float* __restrict__ b3,
        const float* __restrict__ W4, const float* __restrict__ W5,
        const float* __restrict__ W6,
        float* __restrict__ base, unsigned short* __restrict__ wsT) {
    __shared__ float part[32];        // [8 waves][4]
    __shared__ float h1s[4][64];
    __shared__ float embs[4][64];
    int bid = blockIdx.x, tid = threadIdx.x;

    if (tid < 192) {
        int j = bid * 192 + tid;
        int w = j >> 14, rem = j & 16383;
        int k = rem & 127, n = rem >> 7;
        const float* W = (w == 0) ? W4 : ((w == 1) ? W5 : W6);
        float v = W[k * NHID + n];
        int byte = n * 256 + ((2 * k) ^ ((n & 7) << 4));
        *reinterpret_cast<unsigned short*>(
            reinterpret_cast<char*>(wsT) + (size_t)w * 32768 + byte) = f2bf(v);
    }

    int hf = tid >> 7, t = tid & 127;             // task, lane-in-task
    int bb = bid * 4 + hf;                        // 0..1023
    int b = bb >> 6, beta = bb & 63;
    int el = elen[b], bl = blen[b];
    float a0 = 0, a1 = 0, a2 = 0, a3 = 0;
    if (beta < bl) {
        const float* row = SCB + (size_t)bb * NE;
        const int* eis = ei + b * 2 * NE;
        const float* xb = x + b * NN * 2;
        for (int e = t; e < el; e += 128) {
            float tt = fabsf(row[e]);
            int s0 = eis[e], s1 = eis[NE + e];
            float2 v0 = *reinterpret_cast<const float2*>(xb + 2 * s0);
            float2 v1 = *reinterpret_cast<const float2*>(xb + 2 * s1);
            a0 = fmaf(tt, v0.x, a0);
            a1 = fmaf(tt, v0.y, a1);
            a2 = fmaf(tt, v1.x, a2);
            a3 = fmaf(tt, v1.y, a3);
        }
    }
    #pragma unroll
    for (int off = 32; off > 0; off >>= 1) {      // wave64 butterfly
        a0 += __shfl_down(a0, off);
        a1 += __shfl_down(a1, off);
        a2 += __shfl_down(a2, off);
        a3 += __shfl_down(a3, off);
    }
    if ((tid & 63) == 0) {
        int w8 = tid >> 6;
        part[w8 * 4 + 0] = a0; part[w8 * 4 + 1] = a1;
        part[w8 * 4 + 2] = a2; part[w8 * 4 + 3] = a3;
    }
    __syncthreads();
    if (t < 64) {
        float v = b1[t];
        #pragma unroll
        for (int i = 0; i < 4; ++i) {
            float si = part[(2 * hf) * 4 + i] + part[(2 * hf + 1) * 4 + i];
            v = fmaf(si, W1[i * 64 + t], v);
        }
        h1s[hf][t] = fmaxf(v, 0.f);
    }
    __syncthreads();
    if (t < 64) {
        float v = b2[t];
        #pragma unroll 8
        for (int k = 0; k < 64; ++k) v = fmaf(h1s[hf][k], W2[k * 64 + t], v);
        embs[hf][t] = v;
    }
    __syncthreads();
    {
        float v = b3[t];
        #pragma unroll 8
        for (int k = 0; k < 64; ++k) v = fmaf(embs[hf][k], W3[k * NHID + t], v);
        base[(size_t)bb * NHID + t] = v;
    }
}

// Kernel 2 (512 blocks x 512): per 32-edge tile, b = bid & 15 interleave.
//   CHANGE vs R4: no baseS staging — phase E reads base rows straight from
//   global (coalesced 512B/wave/row; 64 rows x 512B = 32KB = L1-resident;
//   per-beta loads independent -> pipelined). LDS 64K -> 48K = 3 blocks/CU.
//   Everything else verbatim from the verified R4 kernel.
__global__ __launch_bounds__(512) void k_fused(
        const float* __restrict__ x, const int* __restrict__ ei,
        const float* __restrict__ SCB,
        const int* __restrict__ elen, const int* __restrict__ blen,
        const float* __restrict__ W3,
        const float* __restrict__ base, const unsigned short* __restrict__ wsT,
        const float* __restrict__ b4, const float* __restrict__ b5,
        const float* __restrict__ b6,
        float* __restrict__ out) {
    int bid = blockIdx.x, tid = threadIdx.x;
    int b = bid & 15;
    int e0 = (bid >> 4) * 32;
    int el = elen[b];
    if (e0 >= el) {                       // fully-padded tile: zero and leave
        float4 z; z.x = 0.f; z.y = 0.f; z.z = 0.f; z.w = 0.f;
        float4* o4 = reinterpret_cast<float4*>(out) + (size_t)(b * NE + e0) * (NHID / 4);
        o4[tid] = z;
        o4[tid + 512] = z;
        return;
    }
    int bl = blen[b];

    __shared__ __align__(16) char lds[49152];
    char*  wS    = lds;                                       // 32K (phase F)
    float* tS    = reinterpret_cast<float*>(lds + 32768);     // 8K [beta][32]
    float4* efS  = reinterpret_cast<float4*>(lds + 40960);    // 512 B
    float* w3r   = reinterpret_cast<float*>(lds + 41472);     // 2 K
    char* io0 = lds + 32768;              // 8K A-tile / L5 out (over tS, post-E)
    char* io1 = lds + 40960;              // 8K L4 out (over efS/w3r, post-S2)

    const float4* w4src = reinterpret_cast<const float4*>(wsT);
    const float4* w5src = reinterpret_cast<const float4*>(
        reinterpret_cast<const char*>(wsT) + 32768);
    const float4* w6src = reinterpret_cast<const float4*>(
        reinterpret_cast<const char*>(wsT) + 65536);
    float4 pw0, pw1, pw2, pw3;            // in-flight weight tile

    {   // stage (|SCB| tile, edge feats, W3 rows 64..67) + W4 prefetch
        {
            int row = tid >> 3, c4 = tid & 7;
            float4 v = *reinterpret_cast<const float4*>(
                SCB + (size_t)(b * NBETA + row) * NE + e0 + c4 * 4);
            v.x = fabsf(v.x); v.y = fabsf(v.y); v.z = fabsf(v.z); v.w = fabsf(v.w);
            reinterpret_cast<float4*>(tS)[tid] = v;
        }
        if (tid < 64) {
            int e = tid >> 1, hf = tid & 1;
            int idx = ei[b * 2 * NE + hf * NE + e0 + e];
            float2 v2 = *reinterpret_cast<const float2*>(x + b * NN * 2 + idx * 2);
            reinterpret_cast<float2*>(&efS[e])[hf] = v2;
        }
        w3r[tid] = W3[64 * NHID + tid];
        pw0 = w4src[tid];        pw1 = w4src[tid + 512];     // issued last ->
        pw2 = w4src[tid + 1024]; pw3 = w4src[tid + 1536];    // stay in flight
    }
    __syncthreads();

    // ---------------- Phase E (base read from global/L1) ----------------
    int cg = tid & 31, es = tid >> 5;       // cg: f32x4 channel group; edges es*2+j
    f32x4 w0  = reinterpret_cast<const f32x4*>(w3r)[cg];
    f32x4 w1  = reinterpret_cast<const f32x4*>(w3r)[32 + cg];
    f32x4 w2  = reinterpret_cast<const f32x4*>(w3r)[64 + cg];
    f32x4 w3v = reinterpret_cast<const f32x4*>(w3r)[96 + cg];
    f32x4 gv[2], acc[2];
    #pragma unroll
    for (int j = 0; j < 2; ++j) {
        float4 e4 = efS[es * 2 + j];
        f32x4 g = w3v * splat4(e4.w);
        g = __builtin_elementwise_fma(splat4(e4.z), w2, g);
        g = __builtin_elementwise_fma(splat4(e4.y), w1, g);
        g = __builtin_elementwise_fma(splat4(e4.x), w0, g);
        gv[j] = g;
        acc[j] = splat4(0.f);
    }
    const f32x4* base4 = reinterpret_cast<const f32x4*>(
        base + (size_t)b * NBETA * NHID);            // GLOBAL, not LDS
    const f32x4 zero = splat4(0.f);
    #pragma unroll 4
    for (int beta = 0; beta < bl; ++beta) {
        f32x4 bs = base4[beta * 32 + cg];
        float2 tv = *reinterpret_cast<const float2*>(tS + beta * 32 + es * 2);
        acc[0] += __builtin_elementwise_max(
            __builtin_elementwise_fma(splat4(tv.x), gv[0], bs), zero);
        acc[1] += __builtin_elementwise_max(
            __builtin_elementwise_fma(splat4(tv.y), gv[1], bs), zero);
    }
    if (bl < NBETA) {
        f32x4 bp = base4[bl * 32 + cg];              // any padded row == base_pad
        f32x4 r = __builtin_elementwise_max(bp, zero);
        f32x4 fcv = splat4((float)(NBETA - bl));
        acc[0] = __builtin_elementwise_fma(fcv, r, acc[0]);
        acc[1] = __builtin_elementwise_fma(fcv, r, acc[1]);
    }
    __syncthreads();   // S1: tS/efS/w3r all dead

    // A-tile (bf16, XOR-swizzled) into io0; commit W4; prefetch W5
    #pragma unroll
    for (int j = 0; j < 2; ++j) {
        int rl = es * 2 + j;
        int byte = rl * 256 + ((cg * 8) ^ ((rl & 7) << 4));
        ushort4 u;
        u.x = f2bf(acc[j].x); u.y = f2bf(acc[j].y);
        u.z = f2bf(acc[j].z); u.w = f2bf(acc[j].w);
        *reinterpret_cast<ushort4*>(io0 + byte) = u;
    }
    float4* wd = reinterpret_cast<float4*>(wS);
    wd[tid] = pw0; wd[tid + 512] = pw1; wd[tid + 1024] = pw2; wd[tid + 1536] = pw3;
    pw0 = w5src[tid];        pw1 = w5src[tid + 512];
    pw2 = w5src[tid + 1024]; pw3 = w5src[tid + 1536];
    __syncthreads();   // S2: A + W4 visible

    // ---------------- Phase F: 3-layer bf16 MFMA GEMM (32x128 @ 128x128) ----
    int l = tid & 63, wid = tid >> 6;
    int wm = wid & 1, wn = wid >> 1;           // 2M x 4N waves over 32x128
    const int lrow = l & 15;
    const int kbl = (l >> 4) * 16;             // byte offset of lane's 8 bf16

    auto layerc = [&](const char* ioIn, char* ioOut, const float* bias,
                      float bscale, bool doRelu, bool final_) {
        f32x4 facc[2];
        facc[0] = splat4(0.f); facc[1] = splat4(0.f);
        int rowA = wm * 16 + lrow;
        #pragma unroll
        for (int ks = 0; ks < 4; ++ks) {
            int kbyte = ks * 64 + kbl;
            short8 a = *reinterpret_cast<const short8*>(
                ioIn + rowA * 256 + (kbyte ^ ((rowA & 7) << 4)));
            #pragma unroll
            for (int nf = 0; nf < 2; ++nf) {
                int col = wn * 32 + nf * 16 + lrow;
                short8 bf = *reinterpret_cast<const short8*>(
                    wS + col * 256 + (kbyte ^ ((col & 7) << 4)));
                facc[nf] = __builtin_amdgcn_mfma_f32_16x16x32_bf16(a, bf, facc[nf], 0, 0, 0);
            }
        }
        #pragma unroll
        for (int nf = 0; nf < 2; ++nf) {
            int colg = wn * 32 + nf * 16 + lrow;
            float bvv = bias[colg];
            #pragma unroll
            for (int r = 0; r < 4; ++r) {
                int row = wm * 16 + (l >> 4) * 4 + r;
                float v = fmaf(bscale, bvv, facc[nf][r]);
                if (doRelu) v = fmaxf(v, 0.f);
                if (!final_) {
                    *reinterpret_cast<unsigned short*>(
                        ioOut + row * 256 + ((colg * 2) ^ ((row & 7) << 4))) = f2bf(v);
                } else {
                    int eg = e0 + row;
                    float vv = (eg >= el) ? 0.f : v;
                    out[(size_t)(b * NE + eg) * NHID + colg] = vv;
                }
            }
        }
    };

    layerc(io0, io1, b4, 64.f, false, false);      // h = hacc@W4 + 64*b4
    __syncthreads();   // S3: W4/io0 reads done
    wd[tid] = pw0; wd[tid + 512] = pw1; wd[tid + 1024] = pw2; wd[tid + 1536] = pw3;
    pw0 = w6src[tid];        pw1 = w6src[tid + 512];
    pw2 = w6src[tid + 1024]; pw3 = w6src[tid + 1536];
    __syncthreads();   // S4: W5 visible
    layerc(io1, io0, b5, 1.f, true, false);        // u = relu(h@W5 + b5)
    __syncthreads();   // S5: W5/io1 reads done
    wd[tid] = pw0; wd[tid + 512] = pw1; wd[tid + 1024] = pw2; wd[tid + 1536] = pw3;
    __syncthreads();   // S6: W6 visible
    layerc(io0, nullptr, b6, 1.f, false, true);    // out = u@W6 + b6 (masked)
}

extern "C" void kernel_launch(void* const* d_in, const int* in_sizes, int n_in,
                              void* d_out, int out_size, void* d_ws, size_t ws_size,
                              hipStream_t stream) {
    const float* x    = (const float*)d_in[0];
    const float* SCB  = (const float*)d_in[1];
    const int*   ei   = (const int*)d_in[2];
    const int*   elen = (const int*)d_in[3];
    const int*   blen = (const int*)d_in[4];
    const float* W1 = (const float*)d_in[5];  const float* b1 = (const float*)d_in[6];
    const float* W2 = (const float*)d_in[7];  const float* b2 = (const float*)d_in[8];
    const float* W3 = (const float*)d_in[9];  const float* b3 = (const float*)d_in[10];
    const float* W4 = (const float*)d_in[11]; const float* b4 = (const float*)d_in[12];
    const float* W5 = (const float*)d_in[13]; const float* b5 = (const float*)d_in[14];
    const float* W6 = (const float*)d_in[15]; const float* b6 = (const float*)d_in[16];
    float* out = (float*)d_out;

    float* ws = (float*)d_ws;
    float* base = ws;                                                   // 131072 f
    unsigned short* wsT = (unsigned short*)(base + NB * NBETA * NHID);  // 49152 bf16

    hipLaunchKernelGGL(k_base_wt, dim3(256), dim3(512), 0, stream,
                       x, ei, SCB, elen, blen, W1, b1, W2, b2, W3, b3, W4, W5, W6, base, wsT);
    hipLaunchKernelGGL(k_fused, dim3(512), dim3(512), 0, stream,
                       x, ei, SCB, elen, blen, W3, base, wsT, b4, b5, b6, out);
}

// Round 9
// 27.021 us; speedup vs baseline: 5.0673x; 1.0971x over previous
//
#include <hip/hip_runtime.h>
#include <hip/hip_bf16.h>

#define NB   16     // B
#define NN   512    // MAX_N
#define NE   1024   // MAX_E
#define NBETA 64    // MAX_BETA
#define NHID 128

typedef __attribute__((ext_vector_type(8))) short short8;
typedef __attribute__((ext_vector_type(4))) float f32x4;

static __device__ __forceinline__ unsigned short f2bf(float f) {
    unsigned u = __float_as_uint(f);
    return (unsigned short)((u + 0x7fffu + ((u >> 16) & 1u)) >> 16);   // RNE
}

static __device__ __forceinline__ f32x4 splat4(float v) {
    f32x4 r; r.x = v; r.y = v; r.z = v; r.w = v; return r;
}

// ---------------------------------------------------------------------------
// Two-dispatch structure — verified floor (26.96 us, reproduced twice).
// Workspace (floats): base = NB*NBETA*128 (512 KB); wsT = 3*128*128 bf16 (96 KB)
// ---------------------------------------------------------------------------

// Kernel 1 (256 blocks x 512): four (b,beta) tasks/block (128 thr each,
//   wave-shfl butterfly reduce) -> base[]; plus 192 weight elems/block ->
//   bf16 transposed + XOR-swizzled wsT[].
__global__ __launch_bounds__(512) void k_base_wt(
        const float* __restrict__ x, const int* __restrict__ ei,
        const float* __restrict__ SCB,
        const int* __restrict__ elen, const int* __restrict__ blen,
        const float* __restrict__ W1, const float* __restrict__ b1,
        const float* __restrict__ W2, const float* __restrict__ b2,
        const float* __restrict__ W3, const float* __restrict__ b3,
        const float* __restrict__ W4, const float* __restrict__ W5,
        const float* __restrict__ W6,
        float* __restrict__ base, unsigned short* __restrict__ wsT) {
    __shared__ float part[32];        // [8 waves][4]
    __shared__ float h1s[4][64];
    __shared__ float embs[4][64];
    int bid = blockIdx.x, tid = threadIdx.x;

    // --- weight transform: 192 elems/block (256*192 = 49152 total) ---
    if (tid < 192) {
        int j = bid * 192 + tid;
        int w = j >> 14, rem = j & 16383;
        int k = rem & 127, n = rem >> 7;
        const float* W = (w == 0) ? W4 : ((w == 1) ? W5 : W6);
        float v = W[k * NHID + n];
        int byte = n * 256 + ((2 * k) ^ ((n & 7) << 4));
        *reinterpret_cast<unsigned short*>(
            reinterpret_cast<char*>(wsT) + (size_t)w * 32768 + byte) = f2bf(v);
    }

    // --- four (b,beta) tasks per block ---
    int hf = tid >> 7, t = tid & 127;             // task, lane-in-task
    int bb = bid * 4 + hf;                        // 0..1023
    int b = bb >> 6, beta = bb & 63;
    int el = elen[b], bl = blen[b];
    float a0 = 0, a1 = 0, a2 = 0, a3 = 0;
    if (beta < bl) {
        const float* row = SCB + (size_t)bb * NE;
        const int* eis = ei + b * 2 * NE;
        const float* xb = x + b * NN * 2;
        for (int e = t; e < el; e += 128) {
            float tt = fabsf(row[e]);
            int s0 = eis[e], s1 = eis[NE + e];
            float2 v0 = *reinterpret_cast<const float2*>(xb + 2 * s0);
            float2 v1 = *reinterpret_cast<const float2*>(xb + 2 * s1);
            a0 = fmaf(tt, v0.x, a0);
            a1 = fmaf(tt, v0.y, a1);
            a2 = fmaf(tt, v1.x, a2);
            a3 = fmaf(tt, v1.y, a3);
        }
    }
    #pragma unroll
    for (int off = 32; off > 0; off >>= 1) {      // wave64 butterfly
        a0 += __shfl_down(a0, off);
        a1 += __shfl_down(a1, off);
        a2 += __shfl_down(a2, off);
        a3 += __shfl_down(a3, off);
    }
    if ((tid & 63) == 0) {
        int w8 = tid >> 6;
        part[w8 * 4 + 0] = a0; part[w8 * 4 + 1] = a1;
        part[w8 * 4 + 2] = a2; part[w8 * 4 + 3] = a3;
    }
    __syncthreads();
    if (t < 64) {
        float v = b1[t];
        #pragma unroll
        for (int i = 0; i < 4; ++i) {
            float si = part[(2 * hf) * 4 + i] + part[(2 * hf + 1) * 4 + i];
            v = fmaf(si, W1[i * 64 + t], v);
        }
        h1s[hf][t] = fmaxf(v, 0.f);
    }
    __syncthreads();
    if (t < 64) {
        float v = b2[t];
        #pragma unroll 8
        for (int k = 0; k < 64; ++k) v = fmaf(h1s[hf][k], W2[k * 64 + t], v);
        embs[hf][t] = v;
    }
    __syncthreads();
    {
        float v = b3[t];
        #pragma unroll 8
        for (int k = 0; k < 64; ++k) v = fmaf(embs[hf][k], W3[k * NHID + t], v);
        base[(size_t)bb * NHID + t] = v;
    }
}

// Kernel 2 (512 blocks x 512): per 32-edge tile.  b = bid & 15 interleave:
//   consecutive blocks (which co-schedule 2-per-CU) come from different
//   batches -> heavy-bl tiles spread across CUs instead of bunching.
//   Padded tiles (e0 >= el) zero-store and exit.  W4/W5/W6 register-
//   prefetched, committed to LDS post-barrier (no serial global stalls).
__global__ __launch_bounds__(512) void k_fused(
        const float* __restrict__ x, const int* __restrict__ ei,
        const float* __restrict__ SCB,
        const int* __restrict__ elen, const int* __restrict__ blen,
        const float* __restrict__ W3,
        const float* __restrict__ base, const unsigned short* __restrict__ wsT,
        const float* __restrict__ b4, const float* __restrict__ b5,
        const float* __restrict__ b6,
        float* __restrict__ out) {
    int bid = blockIdx.x, tid = threadIdx.x;
    int b = bid & 15;
    int e0 = (bid >> 4) * 32;
    int el = elen[b];
    if (e0 >= el) {                       // fully-padded tile: zero and leave
        float4 z; z.x = 0.f; z.y = 0.f; z.z = 0.f; z.w = 0.f;
        float4* o4 = reinterpret_cast<float4*>(out) + (size_t)(b * NE + e0) * (NHID / 4);
        o4[tid] = z;
        o4[tid + 512] = z;
        return;
    }
    int bl = blen[b];

    __shared__ __align__(16) char lds[65536];
    float* baseS = reinterpret_cast<float*>(lds);             // 32K, dead after E
    char*  wS    = lds + 32768;                               // 32K
    float4* efS  = reinterpret_cast<float4*>(wS);             // 512 B
    float* w3r   = reinterpret_cast<float*>(wS + 512);        // 2 K
    float* tS    = reinterpret_cast<float*>(wS + 8192);       // 8 K [beta][32]
    char* io0 = lds;                                          // 8K A-tile / L5 out
    char* io1 = lds + 8192;                                   // 8K L4 out

    const float4* w4src = reinterpret_cast<const float4*>(wsT);
    const float4* w5src = reinterpret_cast<const float4*>(
        reinterpret_cast<const char*>(wsT) + 32768);
    const float4* w6src = reinterpret_cast<const float4*>(
        reinterpret_cast<const char*>(wsT) + 65536);
    float4 pw0, pw1, pw2, pw3;            // in-flight weight tile

    {   // stage (base, |SCB| tile, edge feats, W3 rows 64..67) + W4 prefetch
        const float4* bsrc = reinterpret_cast<const float4*>(base + (size_t)b * NBETA * NHID);
        float4* bd = reinterpret_cast<float4*>(baseS);
        #pragma unroll
        for (int i = 0; i < 4; ++i) bd[tid + 512 * i] = bsrc[tid + 512 * i];
        {
            int row = tid >> 3, c4 = tid & 7;
            float4 v = *reinterpret_cast<const float4*>(
                SCB + (size_t)(b * NBETA + row) * NE + e0 + c4 * 4);
            v.x = fabsf(v.x); v.y = fabsf(v.y); v.z = fabsf(v.z); v.w = fabsf(v.w);
            reinterpret_cast<float4*>(tS)[tid] = v;
        }
        if (tid < 64) {
            int e = tid >> 1, hf = tid & 1;
            int idx = ei[b * 2 * NE + hf * NE + e0 + e];
            float2 v2 = *reinterpret_cast<const float2*>(x + b * NN * 2 + idx * 2);
            reinterpret_cast<float2*>(&efS[e])[hf] = v2;
        }
        w3r[tid] = W3[64 * NHID + tid];
        pw0 = w4src[tid];        pw1 = w4src[tid + 512];     // issued last ->
        pw2 = w4src[tid + 1024]; pw3 = w4src[tid + 1536];    // stay in flight
    }
    __syncthreads();

    // ---------------- Phase E ----------------
    int cg = tid & 31, es = tid >> 5;       // cg: f32x4 channel group; edges es*2+j
    f32x4 w0  = reinterpret_cast<const f32x4*>(w3r)[cg];
    f32x4 w1  = reinterpret_cast<const f32x4*>(w3r)[32 + cg];
    f32x4 w2  = reinterpret_cast<const f32x4*>(w3r)[64 + cg];
    f32x4 w3v = reinterpret_cast<const f32x4*>(w3r)[96 + cg];
    f32x4 gv[2], acc[2];
    #pragma unroll
    for (int j = 0; j < 2; ++j) {
        float4 e4 = efS[es * 2 + j];
        f32x4 g = w3v * splat4(e4.w);
        g = __builtin_elementwise_fma(splat4(e4.z), w2, g);
        g = __builtin_elementwise_fma(splat4(e4.y), w1, g);
        g = __builtin_elementwise_fma(splat4(e4.x), w0, g);
        gv[j] = g;
        acc[j] = splat4(0.f);
    }
    const f32x4* base4 = reinterpret_cast<const f32x4*>(baseS);
    const f32x4 zero = splat4(0.f);
    for (int beta = 0; beta < bl; ++beta) {
        f32x4 bs = base4[beta * 32 + cg];
        float2 tv = *reinterpret_cast<const float2*>(tS + beta * 32 + es * 2);
        acc[0] += __builtin_elementwise_max(
            __builtin_elementwise_fma(splat4(tv.x), gv[0], bs), zero);
        acc[1] += __builtin_elementwise_max(
            __builtin_elementwise_fma(splat4(tv.y), gv[1], bs), zero);
    }
    if (bl < NBETA) {
        f32x4 bp = base4[bl * 32 + cg];              // any padded row == base_pad
        f32x4 r = __builtin_elementwise_max(bp, zero);
        f32x4 fcv = splat4((float)(NBETA - bl));
        acc[0] = __builtin_elementwise_fma(fcv, r, acc[0]);
        acc[1] = __builtin_elementwise_fma(fcv, r, acc[1]);
    }
    __syncthreads();   // S1: baseS/tS/efS/w3r all dead

    // A-tile (bf16, XOR-swizzled) into io0; commit W4; prefetch W5
    #pragma unroll
    for (int j = 0; j < 2; ++j) {
        int rl = es * 2 + j;
        int byte = rl * 256 + ((cg * 8) ^ ((rl & 7) << 4));
        ushort4 u;
        u.x = f2bf(acc[j].x); u.y = f2bf(acc[j].y);
        u.z = f2bf(acc[j].z); u.w = f2bf(acc[j].w);
        *reinterpret_cast<ushort4*>(io0 + byte) = u;
    }
    float4* wd = reinterpret_cast<float4*>(wS);
    wd[tid] = pw0; wd[tid + 512] = pw1; wd[tid + 1024] = pw2; wd[tid + 1536] = pw3;
    pw0 = w5src[tid];        pw1 = w5src[tid + 512];
    pw2 = w5src[tid + 1024]; pw3 = w5src[tid + 1536];
    __syncthreads();   // S2: A + W4 visible

    // ---------------- Phase F: 3-layer bf16 MFMA GEMM (32x128 @ 128x128) ----
    int l = tid & 63, wid = tid >> 6;
    int wm = wid & 1, wn = wid >> 1;           // 2M x 4N waves over 32x128
    const int lrow = l & 15;
    const int kbl = (l >> 4) * 16;             // byte offset of lane's 8 bf16

    auto layerc = [&](const char* ioIn, char* ioOut, const float* bias,
                      float bscale, bool doRelu, bool final_) {
        f32x4 facc[2];
        facc[0] = splat4(0.f); facc[1] = splat4(0.f);
        int rowA = wm * 16 + lrow;
        #pragma unroll
        for (int ks = 0; ks < 4; ++ks) {
            int kbyte = ks * 64 + kbl;
            short8 a = *reinterpret_cast<const short8*>(
                ioIn + rowA * 256 + (kbyte ^ ((rowA & 7) << 4)));
            #pragma unroll
            for (int nf = 0; nf < 2; ++nf) {
                int col = wn * 32 + nf * 16 + lrow;
                short8 bf = *reinterpret_cast<const short8*>(
                    wS + col * 256 + (kbyte ^ ((col & 7) << 4)));
                facc[nf] = __builtin_amdgcn_mfma_f32_16x16x32_bf16(a, bf, facc[nf], 0, 0, 0);
            }
        }
        #pragma unroll
        for (int nf = 0; nf < 2; ++nf) {
            int colg = wn * 32 + nf * 16 + lrow;
            float bvv = bias[colg];
            #pragma unroll
            for (int r = 0; r < 4; ++r) {
                int row = wm * 16 + (l >> 4) * 4 + r;
                float v = fmaf(bscale, bvv, facc[nf][r]);
                if (doRelu) v = fmaxf(v, 0.f);
                if (!final_) {
                    *reinterpret_cast<unsigned short*>(
                        ioOut + row * 256 + ((colg * 2) ^ ((row & 7) << 4))) = f2bf(v);
                } else {
                    int eg = e0 + row;
                    float vv = (eg >= el) ? 0.f : v;
                    out[(size_t)(b * NE + eg) * NHID + colg] = vv;
                }
            }
        }
    };

    layerc(io0, io1, b4, 64.f, false, false);      // h = hacc@W4 + 64*b4
    __syncthreads();   // S3: W4/io0 reads done
    wd[tid] = pw0; wd[tid + 512] = pw1; wd[tid + 1024] = pw2; wd[tid + 1536] = pw3;
    pw0 = w6src[tid];        pw1 = w6src[tid + 512];
    pw2 = w6src[tid + 1024]; pw3 = w6src[tid + 1536];
    __syncthreads();   // S4: W5 visible
    layerc(io1, io0, b5, 1.f, true, false);        // u = relu(h@W5 + b5)
    __syncthreads();   // S5: W5/io1 reads done
    wd[tid] = pw0; wd[tid + 512] = pw1; wd[tid + 1024] = pw2; wd[tid + 1536] = pw3;
    __syncthreads();   // S6: W6 visible
    layerc(io0, nullptr, b6, 1.f, false, true);    // out = u@W6 + b6 (masked)
}

extern "C" void kernel_launch(void* const* d_in, const int* in_sizes, int n_in,
                              void* d_out, int out_size, void* d_ws, size_t ws_size,
                              hipStream_t stream) {
    const float* x    = (const float*)d_in[0];
    const float* SCB  = (const float*)d_in[1];
    const int*   ei   = (const int*)d_in[2];
    const int*   elen = (const int*)d_in[3];
    const int*   blen = (const int*)d_in[4];
    const float* W1 = (const float*)d_in[5];  const float* b1 = (const float*)d_in[6];
    const float* W2 = (const float*)d_in[7];  const float* b2 = (const float*)d_in[8];
    const float* W3 = (const float*)d_in[9];  const float* b3 = (const float*)d_in[10];
    const float* W4 = (const float*)d_in[11]; const float* b4 = (const float*)d_in[12];
    const float* W5 = (const float*)d_in[13]; const float* b5 = (const float*)d_in[14];
    const float* W6 = (const float*)d_in[15]; const float* b6 = (const float*)d_in[16];
    float* out = (float*)d_out;

    float* ws = (float*)d_ws;
    float* base = ws;                                                   // 131072 f
    unsigned short* wsT = (unsigned short*)(base + NB * NBETA * NHID);  // 49152 bf16

    hipLaunchKernelGGL(k_base_wt, dim3(256), dim3(512), 0, stream,
                       x, ei, SCB, elen, blen, W1, b1, W2, b2, W3, b3, W4, W5, W6, base, wsT);
    hipLaunchKernelGGL(k_fused, dim3(512), dim3(512), 0, stream,
                       x, ei, SCB, elen, blen, W3, base, wsT, b4, b5, b6, out);
}